// Round 5
// baseline (437.990 us; speedup 1.0000x reference)
//
#include <hip/hip_runtime.h>

typedef short v8s __attribute__((ext_vector_type(8)));
typedef float v4f __attribute__((ext_vector_type(4)));

__device__ __forceinline__ short f2bf(float f) {
  union { float f; unsigned u; } v; v.f = f;
  unsigned r = v.u + 0x7FFFu + ((v.u >> 16) & 1u);
  return (short)(r >> 16);
}

// async global->LDS, 16B per lane; LDS dst = wave-uniform base + lane*16
__device__ __forceinline__ void gll16(const short* g, short* l) {
  __builtin_amdgcn_global_load_lds(
      (const __attribute__((address_space(1))) void*)g,
      (__attribute__((address_space(3))) void*)l, 16, 0, 0);
}

// ---------------- elementwise cast x: fp32 -> bf16 ----------------
__global__ void cast_f32_bf16(const float* __restrict__ in, short* __restrict__ out, int n4) {
  int i = blockIdx.x * blockDim.x + threadIdx.x;
  if (i >= n4) return;
  float4 v = ((const float4*)in)[i];
  short4 o;
  o.x = f2bf(v.x); o.y = f2bf(v.y); o.z = f2bf(v.z); o.w = f2bf(v.w);
  ((short4*)out)[i] = o;
}

// ---------------- all weight transposes in one launch ----------------
__global__ void cast_transpose_weights(const float* __restrict__ Wq, const float* __restrict__ Wk,
                                       const float* __restrict__ Wv, const float* __restrict__ Wo,
                                       short* __restrict__ Wqkvt, short* __restrict__ Wot) {
  __shared__ float tile[32][33];
  const int tx = threadIdx.x, ty = threadIdx.y;
  int bx = blockIdx.x;
  const float* src; short* dst; int C, cb;
  if (bx < 64)      { src = Wq; dst = Wqkvt;                        C = 2048; cb = bx; }
  else if (bx < 80) { src = Wk; dst = Wqkvt + (size_t)2048 * 2048;  C = 512;  cb = bx - 64; }
  else if (bx < 96) { src = Wv; dst = Wqkvt + (size_t)2560 * 2048;  C = 512;  cb = bx - 80; }
  else              { src = Wo; dst = Wot;                          C = 2048; cb = bx - 96; }
  const int c0 = cb * 32, r0 = blockIdx.y * 32;
#pragma unroll
  for (int i = 0; i < 4; ++i)
    tile[ty + 8 * i][tx] = src[(size_t)(r0 + ty + 8 * i) * C + c0 + tx];
  __syncthreads();
#pragma unroll
  for (int i = 0; i < 4; ++i)
    dst[(size_t)(c0 + ty + 8 * i) * 2048 + r0 + tx] = f2bf(tile[tx][ty + 8 * i]);
}

// ---------------- V transpose + key-permute out of packed QKV ----------------
// key perm (within 32-key blocks): k -> (k&~31) | q4*8 | hi*4 | r,
// q4=(k>>2)&3, hi=(k>>4)&1, r=k&3.  Aligns PV A-frag packing with S^T C-layout.
__global__ void transpose_v_perm(const short* __restrict__ qkv, short* __restrict__ out) {
  __shared__ short tile[32][33];
  const int tx = threadIdx.x, ty = threadIdx.y;
  const int c0 = blockIdx.x * 32, r0 = blockIdx.y * 32;
  const int z = blockIdx.z;
#pragma unroll
  for (int i = 0; i < 4; ++i)
    tile[ty + 8 * i][tx] = qkv[(size_t)(z * 2048 + r0 + ty + 8 * i) * 3072 + 2560 + c0 + tx];
  __syncthreads();
#pragma unroll
  for (int i = 0; i < 4; ++i) {
    int k = r0 + tx;
    int pk = (k & ~31) | ((((k >> 2) & 3) * 2 + ((k >> 4) & 1)) * 4) | (k & 3);
    out[(size_t)z * 512 * 2048 + (size_t)(c0 + ty + 8 * i) * 2048 + pk] = tile[tx][ty + 8 * i];
  }
}

// ---------------- GEMM: C[M][N] = A[M][K] @ Bt[N][K]^T  (bf16 in) ----------------
// SCALEQ: multiply cols < 2048 by qalpha (pre-scales Q by softmax scale * log2e).
template <int BF16_OUT, int SCALEQ>
__global__ __launch_bounds__(256) void gemm_bt(const short* __restrict__ A,
                                               const short* __restrict__ Bt,
                                               void* __restrict__ Cout,
                                               const float* __restrict__ bias,
                                               int M, int N, int K, float qalpha) {
  __shared__ short As[128 * 32];
  __shared__ short Bs[128 * 32];
  const int tid = threadIdx.x;
  const int m0 = blockIdx.y * 128, n0 = blockIdx.x * 128;
  const int w = tid >> 6, lane = tid & 63, quad = lane >> 4, l16 = lane & 15;
  const int wm = (w >> 1) * 64, wn = (w & 1) * 64;
  v4f acc[4][4] = {};
  const int srow = lane >> 2, scol = (lane & 3) * 8;
  const short* Ap = A + (size_t)(m0 + w * 32 + srow) * K + scol;
  const short* Bp = Bt + (size_t)(n0 + w * 32 + srow) * K + scol;
  short* AsW = &As[(w * 32) * 32 + lane * 8];
  short* BsW = &Bs[(w * 32) * 32 + lane * 8];
  const size_t rstep = (size_t)16 * K;
  for (int k0 = 0; k0 < K; k0 += 32) {
    __syncthreads();
    gll16(Ap, AsW);
    gll16(Ap + rstep, AsW + 16 * 32);
    gll16(Bp, BsW);
    gll16(Bp + rstep, BsW + 16 * 32);
    __syncthreads();
    Ap += 32; Bp += 32;
    v8s af[4], bf[4];
#pragma unroll
    for (int i = 0; i < 4; ++i) af[i] = *(const v8s*)&As[(wm + i * 16 + l16) * 32 + quad * 8];
#pragma unroll
    for (int i = 0; i < 4; ++i) bf[i] = *(const v8s*)&Bs[(wn + i * 16 + l16) * 32 + quad * 8];
#pragma unroll
    for (int mi = 0; mi < 4; ++mi)
#pragma unroll
      for (int ni = 0; ni < 4; ++ni)
        acc[mi][ni] = __builtin_amdgcn_mfma_f32_16x16x32_bf16(af[mi], bf[ni], acc[mi][ni], 0, 0, 0);
  }
#pragma unroll
  for (int mi = 0; mi < 4; ++mi) {
#pragma unroll
    for (int ni = 0; ni < 4; ++ni) {
      const int col = n0 + wn + ni * 16 + l16;
      const float cs = (SCALEQ && col < 2048) ? qalpha : 1.0f;
#pragma unroll
      for (int r = 0; r < 4; ++r) {
        const int row = m0 + wm + mi * 16 + quad * 4 + r;
        if (BF16_OUT) {
          ((short*)Cout)[(size_t)row * N + col] = f2bf(acc[mi][ni][r] * cs);
        } else {
          ((float*)Cout)[(size_t)row * N + col] = acc[mi][ni][r] + bias[col];
        }
      }
    }
  }
}

// ---------------- flash attention v5 ----------------
// grid (8, 32): block = paired 128-row q-tiles (qt=bx, 15-bx) -> uniform 17 k-tiles
// of 128 keys. 512 threads = 8 waves (2 wq x 4 wk); wave = 64 q x 32 keys ->
// 16 ds_read_b128 per 68 MFMAs, 2 waves/SIMD (vs R4's 1) to hide latency.
// Q pre-scaled by scale*log2e in the QKV GEMM -> softmax is bare exp2.
// o/l summed across the 4 wk waves via a serial LDS chain at epilogue.
__global__ __launch_bounds__(512, 2) void flash_attn5(const short* __restrict__ QKV,
                                                      const short* __restrict__ Vtb,
                                                      short* __restrict__ ctx) {
  __shared__ __align__(16) short smem[32768];  // Ks 128x128 | Vs 128x128 (64 KB)
  short* Ks = smem;
  short* Vs = smem + 16384;
  const int tid = threadIdx.x;
  const int w = tid >> 6, lane = tid & 63, quad = lane >> 4, l16 = lane & 15;
  const int wq = w >> 2, wk = w & 3;
  const int bh = blockIdx.y;
  const int b = bh >> 4, h = bh & 15, g = h >> 2;
  v8s ones;
#pragma unroll
  for (int i = 0; i < 8; ++i) ones[i] = (short)0x3F80;

  // staging roles: wave w stages K rows/V d-rows w*16 + ii*4 + (lane>>4), slot lane&15
  const int srow0 = w * 16 + (lane >> 4);
  const int slot = lane & 15;
  short* kdst = Ks + srow0 * 128 + slot * 8;
  short* vdst = Vs + srow0 * 128 + slot * 8;
  const short* Kg0 = QKV + (size_t)(b * 2048 + srow0) * 3072 + 2048 + g * 128;
  const short* Vg0 = Vtb + (size_t)(b * 512 + g * 128 + srow0) * 2048;

  float* red = (float*)smem;

#pragma unroll 1
  for (int half = 0; half < 2; ++half) {
    const int qt = half ? (15 - blockIdx.x) : blockIdx.x;
    const int q0 = qt * 128;
    const int qb = q0 + wq * 64;

    // Q fragments: 4 qsets of 16 rows (MFMA B-operand for S^T = K*Q^T); pre-scaled
    v8s aq[4][4];
#pragma unroll
    for (int qs = 0; qs < 4; ++qs) {
      const short* Qp = QKV + (size_t)(b * 2048 + qb + qs * 16 + l16) * 3072 + h * 128 + quad * 8;
#pragma unroll
      for (int kk = 0; kk < 4; ++kk) aq[qs][kk] = *(const v8s*)(Qp + kk * 32);
    }
    v4f o[4][8] = {};
    v4f ol[4] = {};

    const int nk = qt + 1;
#pragma unroll 1
    for (int kt = 0; kt < nk; ++kt) {
      const int key0 = kt << 7;
      __syncthreads();  // previous compute / epilogue readers done with smem
      {
#pragma unroll
        for (int ii = 0; ii < 4; ++ii) {
          const int rlow = (lane >> 4) + ii * 4;          // (row & 15)
          gll16(Kg0 + (size_t)(key0 + ii * 4) * 3072 + (slot ^ rlow) * 8, kdst + ii * 4 * 128);
          gll16(Vg0 + (size_t)(ii * 4) * 2048 + key0 + (slot ^ rlow) * 8, vdst + ii * 4 * 128);
        }
      }
      __syncthreads();  // staging drained (vmcnt 0) + visible

      const int kb = key0 + wk * 32;
      if (kb > qb + 63) continue;  // wave-uniform: fully masked

      // S^T = K @ Q^T for this wave's 32 keys x 64 q
      v4f sf[4][2] = {};
#pragma unroll
      for (int kfl = 0; kfl < 2; ++kfl)
#pragma unroll
        for (int kk = 0; kk < 4; ++kk) {
          v8s kfr = *(const v8s*)&Ks[(wk * 32 + kfl * 16 + l16) * 128 + (((kk * 4 + quad) ^ l16) * 8)];
#pragma unroll
          for (int qs = 0; qs < 4; ++qs)
            sf[qs][kfl] = __builtin_amdgcn_mfma_f32_16x16x32_bf16(kfr, aq[qs][kk], sf[qs][kfl], 0, 0, 0);
        }
      // mask + exp2 + pack P^T C-layout -> PV A-frag (32 keys)
      const bool diag = (kb + 31 > qb);
      v8s pa[4];
#pragma unroll
      for (int qs = 0; qs < 4; ++qs) {
        const int qg = qb + qs * 16 + l16;
        v8s t;
#pragma unroll
        for (int kfl = 0; kfl < 2; ++kfl)
#pragma unroll
          for (int r = 0; r < 4; ++r) {
            float s = sf[qs][kfl][r];
            if (diag && (kb + kfl * 16 + quad * 4 + r > qg)) s = -1e30f;
            t[kfl * 4 + r] = f2bf(exp2f(s));
          }
        pa[qs] = t;
      }
      // O += P @ V ; l += P @ 1
#pragma unroll
      for (int nf = 0; nf < 8; ++nf) {
        v8s vf = *(const v8s*)&Vs[(nf * 16 + l16) * 128 + (((wk * 4 + quad) ^ l16) * 8)];
#pragma unroll
        for (int qs = 0; qs < 4; ++qs)
          o[qs][nf] = __builtin_amdgcn_mfma_f32_16x16x32_bf16(pa[qs], vf, o[qs][nf], 0, 0, 0);
      }
#pragma unroll
      for (int qs = 0; qs < 4; ++qs)
        ol[qs] = __builtin_amdgcn_mfma_f32_16x16x32_bf16(pa[qs], ones, ol[qs], 0, 0, 0);
    }

    // ---- epilogue: sum o/l across the 4 wk waves, normalize, store ----
    __syncthreads();  // K/V LDS reads done; smem becomes reduction buffer
    // phase L: all waves write ol (32 KB region), wk0 sums
#pragma unroll
    for (int qs = 0; qs < 4; ++qs)
      *(v4f*)&red[(((wk * 2 + wq) * 4 + qs) * 256) + l16 * 16 + quad * 4] = ol[qs];
    __syncthreads();
    float inv[4][4];
    if (wk == 0) {
#pragma unroll
      for (int qs = 0; qs < 4; ++qs) {
        v4f lsum = ol[qs];
#pragma unroll
        for (int j = 1; j < 4; ++j)
          lsum += *(const v4f*)&red[(((j * 2 + wq) * 4 + qs) * 256) + l16 * 16 + quad * 4];
#pragma unroll
        for (int r = 0; r < 4; ++r) inv[qs][r] = 1.0f / lsum[r];
      }
    }
    __syncthreads();
    // phase O: serial chain wk3 -> wk2 -> wk1 -> wk0 (full 64 KB region)
    if (wk == 3) {
#pragma unroll
      for (int qs = 0; qs < 4; ++qs)
#pragma unroll
        for (int nf = 0; nf < 8; ++nf)
          *(v4f*)&red[((((wq * 4 + qs) * 8 + nf) * 256)) + l16 * 16 + quad * 4] = o[qs][nf];
    }
    __syncthreads();
    if (wk == 2) {
#pragma unroll
      for (int qs = 0; qs < 4; ++qs)
#pragma unroll
        for (int nf = 0; nf < 8; ++nf) {
          float* p = &red[((((wq * 4 + qs) * 8 + nf) * 256)) + l16 * 16 + quad * 4];
          *(v4f*)p = o[qs][nf] + *(const v4f*)p;
        }
    }
    __syncthreads();
    if (wk == 1) {
#pragma unroll
      for (int qs = 0; qs < 4; ++qs)
#pragma unroll
        for (int nf = 0; nf < 8; ++nf) {
          float* p = &red[((((wq * 4 + qs) * 8 + nf) * 256)) + l16 * 16 + quad * 4];
          *(v4f*)p = o[qs][nf] + *(const v4f*)p;
        }
    }
    __syncthreads();
    if (wk == 0) {
#pragma unroll
      for (int qs = 0; qs < 4; ++qs)
#pragma unroll
        for (int nf = 0; nf < 8; ++nf) {
          v4f osum = o[qs][nf] +
                     *(const v4f*)&red[((((wq * 4 + qs) * 8 + nf) * 256)) + l16 * 16 + quad * 4];
#pragma unroll
          for (int r = 0; r < 4; ++r) {
            const int row = qb + qs * 16 + quad * 4 + r;
            ctx[(size_t)(b * 2048 + row) * 2048 + h * 128 + nf * 16 + l16] =
                f2bf(osum[r] * inv[qs][r]);
          }
        }
    }
  }
}

extern "C" void kernel_launch(void* const* d_in, const int* in_sizes, int n_in,
                              void* d_out, int out_size, void* d_ws, size_t ws_size,
                              hipStream_t stream) {
  const float* x = (const float*)d_in[0];
  const float* Wq = (const float*)d_in[1];
  const float* Wk = (const float*)d_in[2];
  const float* Wv = (const float*)d_in[3];
  const float* Wo = (const float*)d_in[4];
  const float* bo = (const float*)d_in[5];
  float* out = (float*)d_out;
  char* ws = (char*)d_ws;

  // workspace layout (bytes), total 64 MiB; ctx aliases xb
  short* xb    = (short*)(ws);             // 16,777,216  x bf16 [4096][2048]
  short* ctx   = (short*)(ws);             // alias       [4096][2048]
  short* Wqkvt = (short*)(ws + 16777216);  // 12,582,912  [3072 n][2048 k] packed Q|K|V
  short* Wot   = (short*)(ws + 29360128);  //  8,388,608  [2048 n][2048 k]
  short* QKV   = (short*)(ws + 37748736);  // 25,165,824  [4096][3072]  (Q pre-scaled)
  short* Vtb   = (short*)(ws + 62914560);  //  4,194,304  [b][512][2048] key-permuted

  const float qalpha = 0.08838834764831845f * 1.4426950408889634f;  // scale * log2(e)

  dim3 tb(32, 8);
  cast_f32_bf16<<<8192, 256, 0, stream>>>(x, xb, 2097152);
  cast_transpose_weights<<<dim3(160, 64), tb, 0, stream>>>(Wq, Wk, Wv, Wo, Wqkvt, Wot);

  gemm_bt<1, 1><<<dim3(24, 32), 256, 0, stream>>>(xb, Wqkvt, (void*)QKV, nullptr, 4096, 3072, 2048, qalpha);

  transpose_v_perm<<<dim3(16, 64, 2), tb, 0, stream>>>(QKV, Vtb);

  flash_attn5<<<dim3(8, 32), 512, 0, stream>>>(QKV, Vtb, ctx);

  gemm_bt<0, 0><<<dim3(16, 32), 256, 0, stream>>>(ctx, Wot, (void*)out, bo, 4096, 2048, 2048, 1.0f);
}

// Round 6
// 434.591 us; speedup vs baseline: 1.0078x; 1.0078x over previous
//
#include <hip/hip_runtime.h>

typedef short v8s __attribute__((ext_vector_type(8)));
typedef float v4f __attribute__((ext_vector_type(4)));

__device__ __forceinline__ short f2bf(float f) {
  union { float f; unsigned u; } v; v.f = f;
  unsigned r = v.u + 0x7FFFu + ((v.u >> 16) & 1u);
  return (short)(r >> 16);
}

// async global->LDS, 16B per lane; LDS dst = wave-uniform base + lane*16
__device__ __forceinline__ void gll16(const short* g, short* l) {
  __builtin_amdgcn_global_load_lds(
      (const __attribute__((address_space(1))) void*)g,
      (__attribute__((address_space(3))) void*)l, 16, 0, 0);
}

// ---------------- elementwise cast x: fp32 -> bf16 ----------------
__global__ void cast_f32_bf16(const float* __restrict__ in, short* __restrict__ out, int n4) {
  int i = blockIdx.x * blockDim.x + threadIdx.x;
  if (i >= n4) return;
  float4 v = ((const float4*)in)[i];
  short4 o;
  o.x = f2bf(v.x); o.y = f2bf(v.y); o.z = f2bf(v.z); o.w = f2bf(v.w);
  ((short4*)out)[i] = o;
}

// ---------------- all weight transposes in one launch ----------------
__global__ void cast_transpose_weights(const float* __restrict__ Wq, const float* __restrict__ Wk,
                                       const float* __restrict__ Wv, const float* __restrict__ Wo,
                                       short* __restrict__ Wqkvt, short* __restrict__ Wot) {
  __shared__ float tile[32][33];
  const int tx = threadIdx.x, ty = threadIdx.y;
  int bx = blockIdx.x;
  const float* src; short* dst; int C, cb;
  if (bx < 64)      { src = Wq; dst = Wqkvt;                        C = 2048; cb = bx; }
  else if (bx < 80) { src = Wk; dst = Wqkvt + (size_t)2048 * 2048;  C = 512;  cb = bx - 64; }
  else if (bx < 96) { src = Wv; dst = Wqkvt + (size_t)2560 * 2048;  C = 512;  cb = bx - 80; }
  else              { src = Wo; dst = Wot;                          C = 2048; cb = bx - 96; }
  const int c0 = cb * 32, r0 = blockIdx.y * 32;
#pragma unroll
  for (int i = 0; i < 4; ++i)
    tile[ty + 8 * i][tx] = src[(size_t)(r0 + ty + 8 * i) * C + c0 + tx];
  __syncthreads();
#pragma unroll
  for (int i = 0; i < 4; ++i)
    dst[(size_t)(c0 + ty + 8 * i) * 2048 + r0 + tx] = f2bf(tile[tx][ty + 8 * i]);
}

// ---------------- V transpose + key-permute out of packed QKV ----------------
// key perm (within 32-key blocks): k -> (k&~31) | q4*8 | hi*4 | r,
// q4=(k>>2)&3, hi=(k>>4)&1, r=k&3.  Aligns PV A-frag packing with S^T C-layout.
__global__ void transpose_v_perm(const short* __restrict__ qkv, short* __restrict__ out) {
  __shared__ short tile[32][33];
  const int tx = threadIdx.x, ty = threadIdx.y;
  const int c0 = blockIdx.x * 32, r0 = blockIdx.y * 32;
  const int z = blockIdx.z;
#pragma unroll
  for (int i = 0; i < 4; ++i)
    tile[ty + 8 * i][tx] = qkv[(size_t)(z * 2048 + r0 + ty + 8 * i) * 3072 + 2560 + c0 + tx];
  __syncthreads();
#pragma unroll
  for (int i = 0; i < 4; ++i) {
    int k = r0 + tx;
    int pk = (k & ~31) | ((((k >> 2) & 3) * 2 + ((k >> 4) & 1)) * 4) | (k & 3);
    out[(size_t)z * 512 * 2048 + (size_t)(c0 + ty + 8 * i) * 2048 + pk] = tile[tx][ty + 8 * i];
  }
}

// ---------------- GEMM: C[M][N] = A[M][K] @ Bt[N][K]^T  (bf16 in) ----------------
// SCALEQ: multiply cols < 2048 by qalpha (pre-scales Q by softmax scale * log2e).
template <int BF16_OUT, int SCALEQ>
__global__ __launch_bounds__(256) void gemm_bt(const short* __restrict__ A,
                                               const short* __restrict__ Bt,
                                               void* __restrict__ Cout,
                                               const float* __restrict__ bias,
                                               int M, int N, int K, float qalpha) {
  __shared__ short As[128 * 32];
  __shared__ short Bs[128 * 32];
  const int tid = threadIdx.x;
  const int m0 = blockIdx.y * 128, n0 = blockIdx.x * 128;
  const int w = tid >> 6, lane = tid & 63, quad = lane >> 4, l16 = lane & 15;
  const int wm = (w >> 1) * 64, wn = (w & 1) * 64;
  v4f acc[4][4] = {};
  const int srow = lane >> 2, scol = (lane & 3) * 8;
  const short* Ap = A + (size_t)(m0 + w * 32 + srow) * K + scol;
  const short* Bp = Bt + (size_t)(n0 + w * 32 + srow) * K + scol;
  short* AsW = &As[(w * 32) * 32 + lane * 8];
  short* BsW = &Bs[(w * 32) * 32 + lane * 8];
  const size_t rstep = (size_t)16 * K;
  for (int k0 = 0; k0 < K; k0 += 32) {
    __syncthreads();
    gll16(Ap, AsW);
    gll16(Ap + rstep, AsW + 16 * 32);
    gll16(Bp, BsW);
    gll16(Bp + rstep, BsW + 16 * 32);
    __syncthreads();
    Ap += 32; Bp += 32;
    v8s af[4], bf[4];
#pragma unroll
    for (int i = 0; i < 4; ++i) af[i] = *(const v8s*)&As[(wm + i * 16 + l16) * 32 + quad * 8];
#pragma unroll
    for (int i = 0; i < 4; ++i) bf[i] = *(const v8s*)&Bs[(wn + i * 16 + l16) * 32 + quad * 8];
#pragma unroll
    for (int mi = 0; mi < 4; ++mi)
#pragma unroll
      for (int ni = 0; ni < 4; ++ni)
        acc[mi][ni] = __builtin_amdgcn_mfma_f32_16x16x32_bf16(af[mi], bf[ni], acc[mi][ni], 0, 0, 0);
  }
#pragma unroll
  for (int mi = 0; mi < 4; ++mi) {
#pragma unroll
    for (int ni = 0; ni < 4; ++ni) {
      const int col = n0 + wn + ni * 16 + l16;
      const float cs = (SCALEQ && col < 2048) ? qalpha : 1.0f;
#pragma unroll
      for (int r = 0; r < 4; ++r) {
        const int row = m0 + wm + mi * 16 + quad * 4 + r;
        if (BF16_OUT) {
          ((short*)Cout)[(size_t)row * N + col] = f2bf(acc[mi][ni][r] * cs);
        } else {
          ((float*)Cout)[(size_t)row * N + col] = acc[mi][ni][r] + bias[col];
        }
      }
    }
  }
}

// ---------------- flash attention v6 ----------------
// grid (8, 32): block = paired 128-row q-tiles (qt=bx, 15-bx) -> uniform 17 k-tiles
// of 128 keys. 512 threads = 8 waves (2 wq x 4 wk); wave = 64 q x 32 keys ->
// 16 ds_read_b128 per 68 MFMAs, 2 waves/SIMD.
// __launch_bounds__(512) ONLY: R5's (512,2) capped VGPR at 128 -> 600 MB scratch
// spills (FETCH 443 MB). Plain (512) caps at 256 (all 8 waves must be resident).
// Q pre-scaled by scale*log2e in the QKV GEMM -> softmax is bare exp2.
__global__ __launch_bounds__(512) void flash_attn6(const short* __restrict__ QKV,
                                                   const short* __restrict__ Vtb,
                                                   short* __restrict__ ctx) {
  __shared__ __align__(16) short smem[32768];  // Ks 128x128 | Vs 128x128 (64 KB)
  short* Ks = smem;
  short* Vs = smem + 16384;
  const int tid = threadIdx.x;
  const int w = tid >> 6, lane = tid & 63, quad = lane >> 4, l16 = lane & 15;
  const int wq = w >> 2, wk = w & 3;
  const int bh = blockIdx.y;
  const int b = bh >> 4, h = bh & 15, g = h >> 2;
  v8s ones;
#pragma unroll
  for (int i = 0; i < 8; ++i) ones[i] = (short)0x3F80;

  // staging roles: wave w stages K rows/V d-rows w*16 + ii*4 + (lane>>4), slot lane&15
  const int srow0 = w * 16 + (lane >> 4);
  const int slot = lane & 15;
  short* kdst = Ks + srow0 * 128 + slot * 8;
  short* vdst = Vs + srow0 * 128 + slot * 8;
  const short* Kg0 = QKV + (size_t)(b * 2048 + srow0) * 3072 + 2048 + g * 128;
  const short* Vg0 = Vtb + (size_t)(b * 512 + g * 128 + srow0) * 2048;

  float* red = (float*)smem;

#pragma unroll 1
  for (int half = 0; half < 2; ++half) {
    const int qt = half ? (15 - blockIdx.x) : blockIdx.x;
    const int q0 = qt * 128;
    const int qb = q0 + wq * 64;

    // Q fragments: 4 qsets of 16 rows (MFMA B-operand for S^T = K*Q^T); pre-scaled
    v8s aq[4][4];
#pragma unroll
    for (int qs = 0; qs < 4; ++qs) {
      const short* Qp = QKV + (size_t)(b * 2048 + qb + qs * 16 + l16) * 3072 + h * 128 + quad * 8;
#pragma unroll
      for (int kk = 0; kk < 4; ++kk) aq[qs][kk] = *(const v8s*)(Qp + kk * 32);
    }
    v4f o[4][8] = {};
    v4f ol[4] = {};

    const int nk = qt + 1;
#pragma unroll 1
    for (int kt = 0; kt < nk; ++kt) {
      const int key0 = kt << 7;
      __syncthreads();  // previous compute / epilogue readers done with smem
      {
#pragma unroll
        for (int ii = 0; ii < 4; ++ii) {
          const int rlow = (lane >> 4) + ii * 4;          // (row & 15)
          gll16(Kg0 + (size_t)(key0 + ii * 4) * 3072 + (slot ^ rlow) * 8, kdst + ii * 4 * 128);
          gll16(Vg0 + (size_t)(ii * 4) * 2048 + key0 + (slot ^ rlow) * 8, vdst + ii * 4 * 128);
        }
      }
      __syncthreads();  // staging drained (vmcnt 0) + visible

      const int kb = key0 + wk * 32;
      if (kb > qb + 63) continue;  // wave-uniform: fully masked

      // S^T = K @ Q^T for this wave's 32 keys x 64 q
      v4f sf[4][2] = {};
#pragma unroll
      for (int kfl = 0; kfl < 2; ++kfl)
#pragma unroll
        for (int kk = 0; kk < 4; ++kk) {
          v8s kfr = *(const v8s*)&Ks[(wk * 32 + kfl * 16 + l16) * 128 + (((kk * 4 + quad) ^ l16) * 8)];
#pragma unroll
          for (int qs = 0; qs < 4; ++qs)
            sf[qs][kfl] = __builtin_amdgcn_mfma_f32_16x16x32_bf16(kfr, aq[qs][kk], sf[qs][kfl], 0, 0, 0);
        }
      // mask + exp2 + pack P^T C-layout -> PV A-frag (32 keys)
      const bool diag = (kb + 31 > qb);
      v8s pa[4];
#pragma unroll
      for (int qs = 0; qs < 4; ++qs) {
        const int qg = qb + qs * 16 + l16;
        v8s t;
#pragma unroll
        for (int kfl = 0; kfl < 2; ++kfl)
#pragma unroll
          for (int r = 0; r < 4; ++r) {
            float s = sf[qs][kfl][r];
            if (diag && (kb + kfl * 16 + quad * 4 + r > qg)) s = -1e30f;
            t[kfl * 4 + r] = f2bf(exp2f(s));
          }
        pa[qs] = t;
      }
      // O += P @ V ; l += P @ 1
#pragma unroll
      for (int nf = 0; nf < 8; ++nf) {
        v8s vf = *(const v8s*)&Vs[(nf * 16 + l16) * 128 + (((wk * 4 + quad) ^ l16) * 8)];
#pragma unroll
        for (int qs = 0; qs < 4; ++qs)
          o[qs][nf] = __builtin_amdgcn_mfma_f32_16x16x32_bf16(pa[qs], vf, o[qs][nf], 0, 0, 0);
      }
#pragma unroll
      for (int qs = 0; qs < 4; ++qs)
        ol[qs] = __builtin_amdgcn_mfma_f32_16x16x32_bf16(pa[qs], ones, ol[qs], 0, 0, 0);
    }

    // ---- epilogue: sum o/l across the 4 wk waves, normalize, store ----
    __syncthreads();  // K/V LDS reads done; smem becomes reduction buffer
    // phase L: all waves write ol (32 KB region), wk0 sums
#pragma unroll
    for (int qs = 0; qs < 4; ++qs)
      *(v4f*)&red[(((wk * 2 + wq) * 4 + qs) * 256) + l16 * 16 + quad * 4] = ol[qs];
    __syncthreads();
    float inv[4][4];
    if (wk == 0) {
#pragma unroll
      for (int qs = 0; qs < 4; ++qs) {
        v4f lsum = ol[qs];
#pragma unroll
        for (int j = 1; j < 4; ++j)
          lsum += *(const v4f*)&red[(((j * 2 + wq) * 4 + qs) * 256) + l16 * 16 + quad * 4];
#pragma unroll
        for (int r = 0; r < 4; ++r) inv[qs][r] = 1.0f / lsum[r];
      }
    }
    __syncthreads();
    // phase O: serial chain wk3 -> wk2 -> wk1 -> wk0 (full 64 KB region)
    if (wk == 3) {
#pragma unroll
      for (int qs = 0; qs < 4; ++qs)
#pragma unroll
        for (int nf = 0; nf < 8; ++nf)
          *(v4f*)&red[((((wq * 4 + qs) * 8 + nf) * 256)) + l16 * 16 + quad * 4] = o[qs][nf];
    }
    __syncthreads();
    if (wk == 2) {
#pragma unroll
      for (int qs = 0; qs < 4; ++qs)
#pragma unroll
        for (int nf = 0; nf < 8; ++nf) {
          float* p = &red[((((wq * 4 + qs) * 8 + nf) * 256)) + l16 * 16 + quad * 4];
          *(v4f*)p = o[qs][nf] + *(const v4f*)p;
        }
    }
    __syncthreads();
    if (wk == 1) {
#pragma unroll
      for (int qs = 0; qs < 4; ++qs)
#pragma unroll
        for (int nf = 0; nf < 8; ++nf) {
          float* p = &red[((((wq * 4 + qs) * 8 + nf) * 256)) + l16 * 16 + quad * 4];
          *(v4f*)p = o[qs][nf] + *(const v4f*)p;
        }
    }
    __syncthreads();
    if (wk == 0) {
#pragma unroll
      for (int qs = 0; qs < 4; ++qs)
#pragma unroll
        for (int nf = 0; nf < 8; ++nf) {
          v4f osum = o[qs][nf] +
                     *(const v4f*)&red[((((wq * 4 + qs) * 8 + nf) * 256)) + l16 * 16 + quad * 4];
#pragma unroll
          for (int r = 0; r < 4; ++r) {
            const int row = qb + qs * 16 + quad * 4 + r;
            ctx[(size_t)(b * 2048 + row) * 2048 + h * 128 + nf * 16 + l16] =
                f2bf(osum[r] * inv[qs][r]);
          }
        }
    }
  }
}

extern "C" void kernel_launch(void* const* d_in, const int* in_sizes, int n_in,
                              void* d_out, int out_size, void* d_ws, size_t ws_size,
                              hipStream_t stream) {
  const float* x = (const float*)d_in[0];
  const float* Wq = (const float*)d_in[1];
  const float* Wk = (const float*)d_in[2];
  const float* Wv = (const float*)d_in[3];
  const float* Wo = (const float*)d_in[4];
  const float* bo = (const float*)d_in[5];
  float* out = (float*)d_out;
  char* ws = (char*)d_ws;

  // workspace layout (bytes), total 64 MiB; ctx aliases xb
  short* xb    = (short*)(ws);             // 16,777,216  x bf16 [4096][2048]
  short* ctx   = (short*)(ws);             // alias       [4096][2048]
  short* Wqkvt = (short*)(ws + 16777216);  // 12,582,912  [3072 n][2048 k] packed Q|K|V
  short* Wot   = (short*)(ws + 29360128);  //  8,388,608  [2048 n][2048 k]
  short* QKV   = (short*)(ws + 37748736);  // 25,165,824  [4096][3072]  (Q pre-scaled)
  short* Vtb   = (short*)(ws + 62914560);  //  4,194,304  [b][512][2048] key-permuted

  const float qalpha = 0.08838834764831845f * 1.4426950408889634f;  // scale * log2(e)

  dim3 tb(32, 8);
  cast_f32_bf16<<<8192, 256, 0, stream>>>(x, xb, 2097152);
  cast_transpose_weights<<<dim3(160, 64), tb, 0, stream>>>(Wq, Wk, Wv, Wo, Wqkvt, Wot);

  gemm_bt<1, 1><<<dim3(24, 32), 256, 0, stream>>>(xb, Wqkvt, (void*)QKV, nullptr, 4096, 3072, 2048, qalpha);

  transpose_v_perm<<<dim3(16, 64, 2), tb, 0, stream>>>(QKV, Vtb);

  flash_attn6<<<dim3(8, 32), 512, 0, stream>>>(QKV, Vtb, ctx);

  gemm_bt<0, 0><<<dim3(16, 32), 256, 0, stream>>>(ctx, Wot, (void*)out, bo, 4096, 2048, 2048, 1.0f);
}